// Round 1
// baseline (423.404 us; speedup 1.0000x reference)
//
#include <hip/hip_runtime.h>
#include <math.h>

// Problem constants (from reference: N=200000, D=256, 2 heads, 2 att iters)
#define NROWS 200000
#define D 256
#define F4_PER_ROW 64   // 256 floats / 4

// Workspace layout (floats)
#define WS_C     0        // 256  : column sum of x
#define WS_OUT1  256      // 512  : per-head out1 = sum(a1 * x)
#define WS_OUT2  768      // 512  : per-head out2 = sum(a2 * a1 * x)
#define WS_H1    1280     // 512  : per-head h1
#define WS_H2    1792     // 512  : per-head h2
#define WS_A     2304     // 2*N  : a1 per row, head0 then head1
#define ZERO_CNT 1280     // zero c + out1 + out2 each launch

// att = sigmoid(s / max(|s|, eps))  (L1-normalize of a single-elem row, then sigmoid)
__device__ __forceinline__ float att_sigmoid(float s) {
    float t = s / fmaxf(fabsf(s), 1e-12f);
    return 1.0f / (1.0f + __expf(-t));
}

__global__ void zero_kernel(float* __restrict__ ws) {
    int i = blockIdx.x * blockDim.x + threadIdx.x;
    if (i < ZERO_CNT) ws[i] = 0.0f;
}

// Column sums of x -> ws[WS_C .. WS_C+255]
__global__ void __launch_bounds__(256) colsum_kernel(const float* __restrict__ x,
                                                     float* __restrict__ ws) {
    const int total = NROWS * F4_PER_ROW;  // 12.8M float4
    int tid = threadIdx.x;
    int stride = gridDim.x * blockDim.x;   // multiple of 64 -> column group fixed per thread
    float4 acc = make_float4(0.f, 0.f, 0.f, 0.f);
    for (int g = blockIdx.x * blockDim.x + tid; g < total; g += stride) {
        float4 v = reinterpret_cast<const float4*>(x)[g];
        acc.x += v.x; acc.y += v.y; acc.z += v.z; acc.w += v.w;
    }
    __shared__ float4 sh[256];
    sh[tid] = acc;
    __syncthreads();
    if (tid < 64) {
        float4 a = sh[tid], b = sh[tid + 64], c = sh[tid + 128], d = sh[tid + 192];
        atomicAdd(&ws[WS_C + tid * 4 + 0], a.x + b.x + c.x + d.x);
        atomicAdd(&ws[WS_C + tid * 4 + 1], a.y + b.y + c.y + d.y);
        atomicAdd(&ws[WS_C + tid * 4 + 2], a.z + b.z + c.z + d.z);
        atomicAdd(&ws[WS_C + tid * 4 + 3], a.w + b.w + c.w + d.w);
    }
}

// h[head][j] = tanh( sum_k (v[head][k]*scale) * W[head][k][j] )
// vstride=0 -> both heads share v (the global mean); vstride=D -> per-head vector
__global__ void hproj_kernel(const float* __restrict__ W,
                             const float* __restrict__ vin, int vstride, float scale,
                             float* __restrict__ hout) {
    int head = blockIdx.x;
    int j = threadIdx.x;
    __shared__ float v[D];
    v[j] = vin[head * vstride + j] * scale;
    __syncthreads();
    const float* Wh = W + head * D * D;
    float acc = 0.0f;
#pragma unroll 8
    for (int k = 0; k < D; ++k) acc = fmaf(v[k], Wh[k * D + j], acc);
    hout[head * D + j] = tanhf(acc);
}

// Pass 1: per row r: s_i = x[r].h1_i ; a1_i = att_sigmoid(s_i); out1_i += a1_i * x[r]
// one wave (64 lanes) per row; lane covers 4 contiguous columns (float4)
__global__ void __launch_bounds__(256) pass1_kernel(const float* __restrict__ x,
                                                    float* __restrict__ ws) {
    const float* h = ws + WS_H1;
    float* out1 = ws + WS_OUT1;
    float* aArr = ws + WS_A;
    int tid = threadIdx.x;
    int lane = tid & 63;
    int wv = tid >> 6;
    int gw = blockIdx.x * 4 + wv;
    int nw = gridDim.x * 4;
    float4 h0v = reinterpret_cast<const float4*>(h)[lane];
    float4 h1v = reinterpret_cast<const float4*>(h + D)[lane];
    float4 acc0 = make_float4(0.f, 0.f, 0.f, 0.f);
    float4 acc1 = make_float4(0.f, 0.f, 0.f, 0.f);
    for (int r = gw; r < NROWS; r += nw) {
        float4 xv = reinterpret_cast<const float4*>(x + (size_t)r * D)[lane];
        float d0 = fmaf(xv.x, h0v.x, fmaf(xv.y, h0v.y, fmaf(xv.z, h0v.z, xv.w * h0v.w)));
        float d1 = fmaf(xv.x, h1v.x, fmaf(xv.y, h1v.y, fmaf(xv.z, h1v.z, xv.w * h1v.w)));
#pragma unroll
        for (int off = 1; off < 64; off <<= 1) {
            d0 += __shfl_xor(d0, off);
            d1 += __shfl_xor(d1, off);
        }
        float a0 = att_sigmoid(d0);
        float a1 = att_sigmoid(d1);
        if (lane == 0) aArr[r] = a0;
        else if (lane == 1) aArr[NROWS + r] = a1;
        acc0.x = fmaf(a0, xv.x, acc0.x);
        acc0.y = fmaf(a0, xv.y, acc0.y);
        acc0.z = fmaf(a0, xv.z, acc0.z);
        acc0.w = fmaf(a0, xv.w, acc0.w);
        acc1.x = fmaf(a1, xv.x, acc1.x);
        acc1.y = fmaf(a1, xv.y, acc1.y);
        acc1.z = fmaf(a1, xv.z, acc1.z);
        acc1.w = fmaf(a1, xv.w, acc1.w);
    }
    __shared__ float4 sh[2][256];
    sh[0][tid] = acc0;
    sh[1][tid] = acc1;
    __syncthreads();
    if (tid < 128) {
        int hh = tid >> 6;
        int t = tid & 63;
        float4 a = sh[hh][t], b = sh[hh][t + 64], c = sh[hh][t + 128], d = sh[hh][t + 192];
        atomicAdd(&out1[hh * D + t * 4 + 0], a.x + b.x + c.x + d.x);
        atomicAdd(&out1[hh * D + t * 4 + 1], a.y + b.y + c.y + d.y);
        atomicAdd(&out1[hh * D + t * 4 + 2], a.z + b.z + c.z + d.z);
        atomicAdd(&out1[hh * D + t * 4 + 3], a.w + b.w + c.w + d.w);
    }
}

// Pass 2: s_i = a1_i * (x[r].h2_i); a2_i = att_sigmoid(s_i); out2_i += (a2_i*a1_i) * x[r]
__global__ void __launch_bounds__(256) pass2_kernel(const float* __restrict__ x,
                                                    float* __restrict__ ws) {
    const float* h = ws + WS_H2;
    float* out2 = ws + WS_OUT2;
    const float* aArr = ws + WS_A;
    int tid = threadIdx.x;
    int lane = tid & 63;
    int wv = tid >> 6;
    int gw = blockIdx.x * 4 + wv;
    int nw = gridDim.x * 4;
    float4 h0v = reinterpret_cast<const float4*>(h)[lane];
    float4 h1v = reinterpret_cast<const float4*>(h + D)[lane];
    float4 acc0 = make_float4(0.f, 0.f, 0.f, 0.f);
    float4 acc1 = make_float4(0.f, 0.f, 0.f, 0.f);
    for (int r = gw; r < NROWS; r += nw) {
        float4 xv = reinterpret_cast<const float4*>(x + (size_t)r * D)[lane];
        float aa0 = aArr[r];
        float aa1 = aArr[NROWS + r];
        float d0 = fmaf(xv.x, h0v.x, fmaf(xv.y, h0v.y, fmaf(xv.z, h0v.z, xv.w * h0v.w)));
        float d1 = fmaf(xv.x, h1v.x, fmaf(xv.y, h1v.y, fmaf(xv.z, h1v.z, xv.w * h1v.w)));
#pragma unroll
        for (int off = 1; off < 64; off <<= 1) {
            d0 += __shfl_xor(d0, off);
            d1 += __shfl_xor(d1, off);
        }
        float w0 = att_sigmoid(aa0 * d0) * aa0;
        float w1 = att_sigmoid(aa1 * d1) * aa1;
        acc0.x = fmaf(w0, xv.x, acc0.x);
        acc0.y = fmaf(w0, xv.y, acc0.y);
        acc0.z = fmaf(w0, xv.z, acc0.z);
        acc0.w = fmaf(w0, xv.w, acc0.w);
        acc1.x = fmaf(w1, xv.x, acc1.x);
        acc1.y = fmaf(w1, xv.y, acc1.y);
        acc1.z = fmaf(w1, xv.z, acc1.z);
        acc1.w = fmaf(w1, xv.w, acc1.w);
    }
    __shared__ float4 sh[2][256];
    sh[0][tid] = acc0;
    sh[1][tid] = acc1;
    __syncthreads();
    if (tid < 128) {
        int hh = tid >> 6;
        int t = tid & 63;
        float4 a = sh[hh][t], b = sh[hh][t + 64], c = sh[hh][t + 128], d = sh[hh][t + 192];
        atomicAdd(&out2[hh * D + t * 4 + 0], a.x + b.x + c.x + d.x);
        atomicAdd(&out2[hh * D + t * 4 + 1], a.y + b.y + c.y + d.y);
        atomicAdd(&out2[hh * D + t * 4 + 2], a.z + b.z + c.z + d.z);
        atomicAdd(&out2[hh * D + t * 4 + 3], a.w + b.w + c.w + d.w);
    }
}

__global__ void writeout_kernel(const float* __restrict__ ws, float* __restrict__ out) {
    int i = blockIdx.x * blockDim.x + threadIdx.x;
    if (i < 2 * D) out[i] = ws[WS_OUT2 + i];
}

extern "C" void kernel_launch(void* const* d_in, const int* in_sizes, int n_in,
                              void* d_out, int out_size, void* d_ws, size_t ws_size,
                              hipStream_t stream) {
    const float* x = (const float*)d_in[0];   // (200000, 256) f32
    const float* W = (const float*)d_in[1];   // (2, 256, 256) f32
    float* out = (float*)d_out;               // (1, 512) f32
    float* ws = (float*)d_ws;

    zero_kernel<<<dim3((ZERO_CNT + 255) / 256), dim3(256), 0, stream>>>(ws);
    colsum_kernel<<<dim3(1024), dim3(256), 0, stream>>>(x, ws);
    hproj_kernel<<<dim3(2), dim3(256), 0, stream>>>(W, ws + WS_C, 0, 1.0f / NROWS, ws + WS_H1);
    pass1_kernel<<<dim3(1024), dim3(256), 0, stream>>>(x, ws);
    hproj_kernel<<<dim3(2), dim3(256), 0, stream>>>(W, ws + WS_OUT1, D, 1.0f / NROWS, ws + WS_H2);
    pass2_kernel<<<dim3(1024), dim3(256), 0, stream>>>(x, ws);
    writeout_kernel<<<dim3(2), dim3(256), 0, stream>>>(ws, out);
}